// Round 10
// baseline (145.969 us; speedup 1.0000x reference)
//
#include <hip/hip_runtime.h>
#include <hip/hip_bf16.h>

#define C_DIM 64
#define N_TOK 4608
#define NBLK  72       // proj blocks per batch (64 tokens each)
#define B_SZ  2
#define MBLKS 144      // attn m-blocks per batch (32 m-tokens each)
#define NSEG  8        // n-segments == waves per attn block
#define SEGLEN (N_TOK / NSEG)   // 576
#define KTILES 288     // N_TOK/16 swizzled 16-row K/Q tiles per batch
#define VTILES 72      // N_TOK/64 swizzled 64-token V tiles per batch
#define OSTR  68       // o_lds padded stride (floats)

typedef __bf16 bf16x8 __attribute__((ext_vector_type(8)));
typedef float  f32x4  __attribute__((ext_vector_type(4)));

// ---------------------------------------------------------------------------
// MEASUREMENT ROUND 2: kernels byte-identical to round 7 (PASS, 105.2 us).
// kernel_launch runs proj once + attn THREE times (idempotent).
// T = 105.2 + 2*attn_us  ->  pins down attn exactly.
// ---------------------------------------------------------------------------

__device__ __forceinline__ void gemm_tile(
    const __hip_bfloat16* wmat, const bf16x8 bin[2], const float* bias,
    int col, int quad, f32x4 acc[4])
{
    #pragma unroll
    for (int ot = 0; ot < 4; ot++) {
        f32x4 a = (f32x4){0.f, 0.f, 0.f, 0.f};
        #pragma unroll
        for (int kh = 0; kh < 2; kh++) {
            bf16x8 wf = *(const bf16x8*)(wmat + (ot * 16 + col) * 72 +
                                         kh * 32 + quad * 8);
            a = __builtin_amdgcn_mfma_f32_16x16x32_bf16(wf, bin[kh], a, 0, 0, 0);
        }
        float4 b4 = *(const float4*)(bias + ot * 16 + quad * 4);
        a[0] += b4.x; a[1] += b4.y; a[2] += b4.z; a[3] += b4.w;
        acc[ot] = a;
    }
}

__global__ __launch_bounds__(256) void proj_kernel(
    const float* __restrict__ x,  const float* __restrict__ h,
    const float* __restrict__ Wq, const float* __restrict__ bq,
    const float* __restrict__ Wk, const float* __restrict__ bk,
    const float* __restrict__ Wv, const float* __restrict__ bv,
    __hip_bfloat16* __restrict__ qS, __hip_bfloat16* __restrict__ kS,
    __hip_bfloat16* __restrict__ vS)
{
    __shared__ __hip_bfloat16 wl[3 * 64 * 72];
    __shared__ __hip_bfloat16 xt[64 * 72];
    __shared__ __hip_bfloat16 ht[64 * 72];
    __shared__ __hip_bfloat16 vl[64 * 72];

    const int b  = blockIdx.x / NBLK;
    const int n0 = (blockIdx.x % NBLK) * 64;
    const int t  = threadIdx.x;

    #pragma unroll
    for (int mat = 0; mat < 3; mat++) {
        const float* W = (mat == 0) ? Wq : ((mat == 1) ? Wk : Wv);
        __hip_bfloat16* wd = wl + mat * (64 * 72);
        #pragma unroll
        for (int i = 0; i < 4; i++) {
            const int ch = i * 256 + t;
            const int o = ch >> 4, c0 = (ch & 15) * 4;
            float4 w4 = *(const float4*)(W + ch * 4);
            union { __hip_bfloat16 e[4]; uint2 v; } pk;
            pk.e[0] = __float2bfloat16(w4.x); pk.e[1] = __float2bfloat16(w4.y);
            pk.e[2] = __float2bfloat16(w4.z); pk.e[3] = __float2bfloat16(w4.w);
            *(uint2*)(wd + o * 72 + c0) = pk.v;
        }
    }
    #pragma unroll
    for (int i = 0; i < 4; i++) {
        const int ch = i * 256 + t;
        const int c = ch >> 4, n4 = (ch & 15) * 4;
        float4 x4 = *(const float4*)(x + (size_t)(b * C_DIM + c) * N_TOK + n0 + n4);
        float4 h4 = *(const float4*)(h + (size_t)(b * C_DIM + c) * N_TOK + n0 + n4);
        xt[(n4 + 0) * 72 + c] = __float2bfloat16(x4.x);
        xt[(n4 + 1) * 72 + c] = __float2bfloat16(x4.y);
        xt[(n4 + 2) * 72 + c] = __float2bfloat16(x4.z);
        xt[(n4 + 3) * 72 + c] = __float2bfloat16(x4.w);
        ht[(n4 + 0) * 72 + c] = __float2bfloat16(h4.x);
        ht[(n4 + 1) * 72 + c] = __float2bfloat16(h4.y);
        ht[(n4 + 2) * 72 + c] = __float2bfloat16(h4.z);
        ht[(n4 + 3) * 72 + c] = __float2bfloat16(h4.w);
    }
    __syncthreads();

    const int wave = t >> 6, lane = t & 63;
    const int col = lane & 15, quad = lane >> 4;

    bf16x8 xb[2], hb[2];
    #pragma unroll
    for (int kh = 0; kh < 2; kh++) {
        xb[kh] = *(const bf16x8*)(xt + (wave * 16 + col) * 72 + kh * 32 + quad * 8);
        hb[kh] = *(const bf16x8*)(ht + (wave * 16 + col) * 72 + kh * 32 + quad * 8);
    }

    f32x4 acc[4];

    gemm_tile(wl + 0 * (64 * 72), xb, bq, col, quad, acc);
    {
        const size_t tile16 = (size_t)b * KTILES + (n0 >> 4) + wave;
        const float SC = 0.125f * 1.44269504088896f;
        #pragma unroll
        for (int ot = 0; ot < 4; ot++) {
            union { __hip_bfloat16 e[4]; uint2 v; } pk;
            #pragma unroll
            for (int r = 0; r < 4; r++) pk.e[r] = __float2bfloat16(acc[ot][r] * SC);
            *(uint2*)(qS + (tile16 << 10) + (ot >> 1) * 512 +
                      ((ot * 2 + (quad >> 1)) & 3) * 128 + col * 8 +
                      (quad & 1) * 4) = pk.v;
        }
    }

    gemm_tile(wl + 1 * (64 * 72), hb, bk, col, quad, acc);
    {
        const int t_l = (wave >> 1) * 2 + ((col >> 2) & 1);
        const int row = ((wave * 2 + (col >> 3)) & 3) * 4 + (col & 3);
        const size_t tile16 = (size_t)b * KTILES + (n0 >> 4) + t_l;
        #pragma unroll
        for (int ot = 0; ot < 4; ot++) {
            union { __hip_bfloat16 e[4]; uint2 v; } pk;
            #pragma unroll
            for (int r = 0; r < 4; r++) pk.e[r] = __float2bfloat16(acc[ot][r]);
            *(uint2*)(kS + (tile16 << 10) + (ot >> 1) * 512 +
                      ((ot * 2 + (quad >> 1)) & 3) * 128 + row * 8 +
                      (quad & 1) * 4) = pk.v;
        }
    }

    gemm_tile(wl + 2 * (64 * 72), hb, bv, col, quad, acc);
    #pragma unroll
    for (int ot = 0; ot < 4; ot++)
        #pragma unroll
        for (int r = 0; r < 4; r++)
            vl[(ot * 16 + quad * 4 + r) * 72 + wave * 16 + col] =
                __float2bfloat16(acc[ot][r]);
    __syncthreads();
    {
        const size_t vbase = ((size_t)(b * VTILES) + (n0 >> 6)) << 12;
        #pragma unroll
        for (int rep = 0; rep < 2; rep++) {
            const int ch = rep * 256 + t;
            const int cc = ch >> 7, hf = (ch >> 6) & 1;
            const int qd = (ch >> 4) & 3, c2 = ch & 15;
            *(uint4*)(vS + vbase + (size_t)ch * 8) =
                *(const uint4*)(vl + (cc * 16 + c2) * 72 + hf * 32 + qd * 8);
        }
    }
}

__global__ __launch_bounds__(512) void attn_kernel(
    const __hip_bfloat16* __restrict__ qS,
    const __hip_bfloat16* __restrict__ kS,
    const __hip_bfloat16* __restrict__ vS,
    float* __restrict__ out)
{
    __shared__ float o_lds[NSEG * 16 * OSTR];
    __shared__ float lstat[NSEG][32];

    const int b    = blockIdx.x / MBLKS;
    const int mblk = blockIdx.x % MBLKS;
    const int wave = threadIdx.x >> 6;
    const int lane = threadIdx.x & 63;
    const int col  = lane & 15;
    const int quad = lane >> 4;
    const int m0   = mblk * 32;

    const __hip_bfloat16* qp =
        qS + (((size_t)b * KTILES + (m0 >> 4)) << 10) + lane * 8;
    const bf16x8 qa0 = *(const bf16x8*)(qp);
    const bf16x8 qa1 = *(const bf16x8*)(qp + 512);
    const bf16x8 qb0 = *(const bf16x8*)(qp + 1024);
    const bf16x8 qb1 = *(const bf16x8*)(qp + 1536);

    f32x4 accO0[4], accO1[4];
    #pragma unroll
    for (int cc = 0; cc < 4; cc++) {
        accO0[cc] = (f32x4){0.f, 0.f, 0.f, 0.f};
        accO1[cc] = (f32x4){0.f, 0.f, 0.f, 0.f};
    }
    float rsum0 = 0.f, rsum1 = 0.f;

    const int nbeg = wave * SEGLEN;

    #pragma unroll 1
    for (int n0 = nbeg; n0 < nbeg + SEGLEN; n0 += 64) {
        const __hip_bfloat16* kt =
            kS + (((size_t)b * KTILES + (n0 >> 4)) << 10) + lane * 8;
        bf16x8 ka[8];
        #pragma unroll
        for (int j = 0; j < 4; j++) {
            ka[2 * j]     = *(const bf16x8*)(kt + (j << 10));
            ka[2 * j + 1] = *(const bf16x8*)(kt + (j << 10) + 512);
        }
        const __hip_bfloat16* vt =
            vS + ((((size_t)b * VTILES) + (n0 >> 6)) << 12) + lane * 8;
        bf16x8 va[8];
        #pragma unroll
        for (int cc = 0; cc < 4; cc++) {
            va[2 * cc]     = *(const bf16x8*)(vt + cc * 1024);
            va[2 * cc + 1] = *(const bf16x8*)(vt + cc * 1024 + 512);
        }

        f32x4 s0[4], s1[4];
        #pragma unroll
        for (int j = 0; j < 4; j++) {
            s0[j] = __builtin_amdgcn_mfma_f32_16x16x32_bf16(
                        ka[2 * j], qa0, (f32x4){0.f, 0.f, 0.f, 0.f}, 0, 0, 0);
            s0[j] = __builtin_amdgcn_mfma_f32_16x16x32_bf16(ka[2 * j + 1], qa1, s0[j], 0, 0, 0);
            s1[j] = __builtin_amdgcn_mfma_f32_16x16x32_bf16(
                        ka[2 * j], qb0, (f32x4){0.f, 0.f, 0.f, 0.f}, 0, 0, 0);
            s1[j] = __builtin_amdgcn_mfma_f32_16x16x32_bf16(ka[2 * j + 1], qb1, s1[j], 0, 0, 0);
        }

        union { __hip_bfloat16 e[8]; bf16x8 v; } p00, p01, p10, p11;
        #pragma unroll
        for (int j = 0; j < 2; j++)
            #pragma unroll
            for (int r = 0; r < 4; r++) {
                float e0 = __builtin_amdgcn_exp2f(s0[j][r]);
                float e1 = __builtin_amdgcn_exp2f(s0[2 + j][r]);
                rsum0 += e0 + e1;
                p00.e[j * 4 + r] = __float2bfloat16(e0);
                p01.e[j * 4 + r] = __float2bfloat16(e1);
                float f0 = __builtin_amdgcn_exp2f(s1[j][r]);
                float f1 = __builtin_amdgcn_exp2f(s1[2 + j][r]);
                rsum1 += f0 + f1;
                p10.e[j * 4 + r] = __float2bfloat16(f0);
                p11.e[j * 4 + r] = __float2bfloat16(f1);
            }

        #pragma unroll
        for (int cc = 0; cc < 4; cc++) {
            accO0[cc] = __builtin_amdgcn_mfma_f32_16x16x32_bf16(va[2 * cc],     p00.v, accO0[cc], 0, 0, 0);
            accO0[cc] = __builtin_amdgcn_mfma_f32_16x16x32_bf16(va[2 * cc + 1], p01.v, accO0[cc], 0, 0, 0);
            accO1[cc] = __builtin_amdgcn_mfma_f32_16x16x32_bf16(va[2 * cc],     p10.v, accO1[cc], 0, 0, 0);
            accO1[cc] = __builtin_amdgcn_mfma_f32_16x16x32_bf16(va[2 * cc + 1], p11.v, accO1[cc], 0, 0, 0);
        }
    }

    rsum0 += __shfl_xor(rsum0, 16);  rsum0 += __shfl_xor(rsum0, 32);
    rsum1 += __shfl_xor(rsum1, 16);  rsum1 += __shfl_xor(rsum1, 32);
    if (quad == 0) {
        lstat[wave][col]      = rsum0;
        lstat[wave][16 + col] = rsum1;
    }

    #pragma unroll
    for (int phase = 0; phase < 2; phase++) {
        const f32x4* accp = phase ? accO1 : accO0;
        #pragma unroll
        for (int cc = 0; cc < 4; cc++)
            *(f32x4*)(o_lds + (wave * 16 + col) * OSTR + cc * 16 + quad * 4) =
                accp[cc];
        __syncthreads();
        if (threadIdx.x < 256) {
            const int m  = threadIdx.x & 15;
            const int cq = threadIdx.x >> 4;
            const int mi = phase * 16 + m;
            float lsum = 0.f;
            f32x4 oacc = (f32x4){0.f, 0.f, 0.f, 0.f};
            #pragma unroll
            for (int sgm = 0; sgm < NSEG; sgm++) {
                lsum += lstat[sgm][mi];
                oacc += *(const f32x4*)(o_lds + (sgm * 16 + m) * OSTR + cq * 4);
            }
            const float inv = 1.0f / lsum;
            #pragma unroll
            for (int r = 0; r < 4; r++) {
                const int c = cq * 4 + r;
                out[(size_t)(b * C_DIM + c) * N_TOK + m0 + phase * 16 + m] =
                    oacc[r] * inv;
            }
        }
        __syncthreads();
    }
}

extern "C" void kernel_launch(void* const* d_in, const int* in_sizes, int n_in,
                              void* d_out, int out_size, void* d_ws, size_t ws_size,
                              hipStream_t stream) {
    const float* x  = (const float*)d_in[0];
    const float* h  = (const float*)d_in[1];
    const float* Wq = (const float*)d_in[2];
    const float* bq = (const float*)d_in[3];
    const float* Wk = (const float*)d_in[4];
    const float* bk = (const float*)d_in[5];
    const float* Wv = (const float*)d_in[6];
    const float* bv = (const float*)d_in[7];
    float* out = (float*)d_out;

    const size_t elems = (size_t)B_SZ * N_TOK * C_DIM;   // 589824
    __hip_bfloat16* qS = (__hip_bfloat16*)d_ws;
    __hip_bfloat16* kS = qS + elems;
    __hip_bfloat16* vS = kS + elems;

    proj_kernel<<<B_SZ * NBLK, 256, 0, stream>>>(x, h, Wq, bq, Wk, bk, Wv, bv,
                                                 qS, kS, vS);
    // MEASUREMENT: attn launched 3x (idempotent). T = 105.2 + 2*attn_us.
    attn_kernel<<<B_SZ * MBLKS, 512, 0, stream>>>(qS, kS, vS, out);
    attn_kernel<<<B_SZ * MBLKS, 512, 0, stream>>>(qS, kS, vS, out);
    attn_kernel<<<B_SZ * MBLKS, 512, 0, stream>>>(qS, kS, vS, out);
}

// Round 11
// 93.351 us; speedup vs baseline: 1.5637x; 1.5637x over previous
//
#include <hip/hip_runtime.h>
#include <hip/hip_bf16.h>

#define C_DIM 64
#define N_TOK 4608
#define NBLK  72       // proj blocks per batch (64 tokens each)
#define B_SZ  2
#define M64BLKS 72     // attn m-blocks per batch (64 m-tokens each)
#define NSEG  8        // n-segments == waves per attn block
#define SEGLEN (N_TOK / NSEG)   // 576
#define KTILES 288     // N_TOK/16 swizzled 16-row K/Q tiles per batch
#define VTILES 72      // N_TOK/64 swizzled 64-token V tiles per batch
#define OSTR  68       // o_lds padded stride (floats)

typedef __bf16 bf16x8 __attribute__((ext_vector_type(8)));
typedef float  f32x4  __attribute__((ext_vector_type(4)));

// ---------------------------------------------------------------------------
// Round 11: attn M=64/block (4 m-subtiles per wave) -> K/V L2 traffic 170 MB,
// grid 144 blocks (1/CU, no tail imbalance). proj unchanged (4.8 us, R9).
// Layouts identical to round 7 (verified): kS token-permuted so S^T C/D regs
// are already PV B-operand fragments; vS fragment-swizzled; no-max softmax.
// ---------------------------------------------------------------------------

__device__ __forceinline__ void gemm_tile(
    const __hip_bfloat16* wmat, const bf16x8 bin[2], const float* bias,
    int col, int quad, f32x4 acc[4])
{
    #pragma unroll
    for (int ot = 0; ot < 4; ot++) {
        f32x4 a = (f32x4){0.f, 0.f, 0.f, 0.f};
        #pragma unroll
        for (int kh = 0; kh < 2; kh++) {
            bf16x8 wf = *(const bf16x8*)(wmat + (ot * 16 + col) * 72 +
                                         kh * 32 + quad * 8);
            a = __builtin_amdgcn_mfma_f32_16x16x32_bf16(wf, bin[kh], a, 0, 0, 0);
        }
        float4 b4 = *(const float4*)(bias + ot * 16 + quad * 4);
        a[0] += b4.x; a[1] += b4.y; a[2] += b4.z; a[3] += b4.w;
        acc[ot] = a;
    }
}

__global__ __launch_bounds__(256) void proj_kernel(
    const float* __restrict__ x,  const float* __restrict__ h,
    const float* __restrict__ Wq, const float* __restrict__ bq,
    const float* __restrict__ Wk, const float* __restrict__ bk,
    const float* __restrict__ Wv, const float* __restrict__ bv,
    __hip_bfloat16* __restrict__ qS, __hip_bfloat16* __restrict__ kS,
    __hip_bfloat16* __restrict__ vS)
{
    __shared__ __hip_bfloat16 wl[3 * 64 * 72];
    __shared__ __hip_bfloat16 xt[64 * 72];
    __shared__ __hip_bfloat16 ht[64 * 72];
    __shared__ __hip_bfloat16 vl[64 * 72];

    const int b  = blockIdx.x / NBLK;
    const int n0 = (blockIdx.x % NBLK) * 64;
    const int t  = threadIdx.x;

    #pragma unroll
    for (int mat = 0; mat < 3; mat++) {
        const float* W = (mat == 0) ? Wq : ((mat == 1) ? Wk : Wv);
        __hip_bfloat16* wd = wl + mat * (64 * 72);
        #pragma unroll
        for (int i = 0; i < 4; i++) {
            const int ch = i * 256 + t;
            const int o = ch >> 4, c0 = (ch & 15) * 4;
            float4 w4 = *(const float4*)(W + ch * 4);
            union { __hip_bfloat16 e[4]; uint2 v; } pk;
            pk.e[0] = __float2bfloat16(w4.x); pk.e[1] = __float2bfloat16(w4.y);
            pk.e[2] = __float2bfloat16(w4.z); pk.e[3] = __float2bfloat16(w4.w);
            *(uint2*)(wd + o * 72 + c0) = pk.v;
        }
    }
    #pragma unroll
    for (int i = 0; i < 4; i++) {
        const int ch = i * 256 + t;
        const int c = ch >> 4, n4 = (ch & 15) * 4;
        float4 x4 = *(const float4*)(x + (size_t)(b * C_DIM + c) * N_TOK + n0 + n4);
        float4 h4 = *(const float4*)(h + (size_t)(b * C_DIM + c) * N_TOK + n0 + n4);
        xt[(n4 + 0) * 72 + c] = __float2bfloat16(x4.x);
        xt[(n4 + 1) * 72 + c] = __float2bfloat16(x4.y);
        xt[(n4 + 2) * 72 + c] = __float2bfloat16(x4.z);
        xt[(n4 + 3) * 72 + c] = __float2bfloat16(x4.w);
        ht[(n4 + 0) * 72 + c] = __float2bfloat16(h4.x);
        ht[(n4 + 1) * 72 + c] = __float2bfloat16(h4.y);
        ht[(n4 + 2) * 72 + c] = __float2bfloat16(h4.z);
        ht[(n4 + 3) * 72 + c] = __float2bfloat16(h4.w);
    }
    __syncthreads();

    const int wave = t >> 6, lane = t & 63;
    const int col = lane & 15, quad = lane >> 4;

    bf16x8 xb[2], hb[2];
    #pragma unroll
    for (int kh = 0; kh < 2; kh++) {
        xb[kh] = *(const bf16x8*)(xt + (wave * 16 + col) * 72 + kh * 32 + quad * 8);
        hb[kh] = *(const bf16x8*)(ht + (wave * 16 + col) * 72 + kh * 32 + quad * 8);
    }

    f32x4 acc[4];

    gemm_tile(wl + 0 * (64 * 72), xb, bq, col, quad, acc);
    {
        const size_t tile16 = (size_t)b * KTILES + (n0 >> 4) + wave;
        const float SC = 0.125f * 1.44269504088896f;
        #pragma unroll
        for (int ot = 0; ot < 4; ot++) {
            union { __hip_bfloat16 e[4]; uint2 v; } pk;
            #pragma unroll
            for (int r = 0; r < 4; r++) pk.e[r] = __float2bfloat16(acc[ot][r] * SC);
            *(uint2*)(qS + (tile16 << 10) + (ot >> 1) * 512 +
                      ((ot * 2 + (quad >> 1)) & 3) * 128 + col * 8 +
                      (quad & 1) * 4) = pk.v;
        }
    }

    gemm_tile(wl + 1 * (64 * 72), hb, bk, col, quad, acc);
    {
        const int t_l = (wave >> 1) * 2 + ((col >> 2) & 1);
        const int row = ((wave * 2 + (col >> 3)) & 3) * 4 + (col & 3);
        const size_t tile16 = (size_t)b * KTILES + (n0 >> 4) + t_l;
        #pragma unroll
        for (int ot = 0; ot < 4; ot++) {
            union { __hip_bfloat16 e[4]; uint2 v; } pk;
            #pragma unroll
            for (int r = 0; r < 4; r++) pk.e[r] = __float2bfloat16(acc[ot][r]);
            *(uint2*)(kS + (tile16 << 10) + (ot >> 1) * 512 +
                      ((ot * 2 + (quad >> 1)) & 3) * 128 + row * 8 +
                      (quad & 1) * 4) = pk.v;
        }
    }

    gemm_tile(wl + 2 * (64 * 72), hb, bv, col, quad, acc);
    #pragma unroll
    for (int ot = 0; ot < 4; ot++)
        #pragma unroll
        for (int r = 0; r < 4; r++)
            vl[(ot * 16 + quad * 4 + r) * 72 + wave * 16 + col] =
                __float2bfloat16(acc[ot][r]);
    __syncthreads();
    {
        const size_t vbase = ((size_t)(b * VTILES) + (n0 >> 6)) << 12;
        #pragma unroll
        for (int rep = 0; rep < 2; rep++) {
            const int ch = rep * 256 + t;
            const int cc = ch >> 7, hf = (ch >> 6) & 1;
            const int qd = (ch >> 4) & 3, c2 = ch & 15;
            *(uint4*)(vS + vbase + (size_t)ch * 8) =
                *(const uint4*)(vl + (cc * 16 + c2) * 72 + hf * 32 + qd * 8);
        }
    }
}

// ---------------------------------------------------------------------------
// Flash attention, M=64 per block. 8 waves; each wave owns all 4 m-subtiles
// and 1/8 of n (576 tokens). K/V fragment loads amortized over 64 m-rows.
// Barrier-free inner loop (round-7 scheme). grid = B*72 blocks of 512.
// ---------------------------------------------------------------------------
__global__ __launch_bounds__(512) void attn_kernel(
    const __hip_bfloat16* __restrict__ qS,
    const __hip_bfloat16* __restrict__ kS,
    const __hip_bfloat16* __restrict__ vS,
    float* __restrict__ out)
{
    __shared__ float o_lds[NSEG * 16 * OSTR];
    __shared__ float lstat[NSEG][64];

    const int b    = blockIdx.x / M64BLKS;
    const int mblk = blockIdx.x % M64BLKS;
    const int wave = threadIdx.x >> 6;
    const int lane = threadIdx.x & 63;
    const int col  = lane & 15;
    const int quad = lane >> 4;
    const int m0   = mblk * 64;

    // loop-invariant Q fragments for the 4 m-subtiles (contiguous 1KB loads)
    const __hip_bfloat16* qp =
        qS + (((size_t)b * KTILES + (m0 >> 4)) << 10) + lane * 8;
    bf16x8 qa[4][2];
    #pragma unroll
    for (int ms = 0; ms < 4; ms++) {
        qa[ms][0] = *(const bf16x8*)(qp + ms * 1024);
        qa[ms][1] = *(const bf16x8*)(qp + ms * 1024 + 512);
    }

    f32x4 accO[4][4];
    #pragma unroll
    for (int ms = 0; ms < 4; ms++)
        #pragma unroll
        for (int cc = 0; cc < 4; cc++)
            accO[ms][cc] = (f32x4){0.f, 0.f, 0.f, 0.f};
    float rsum[4] = {0.f, 0.f, 0.f, 0.f};

    const int nbeg = wave * SEGLEN;

    #pragma unroll 1
    for (int n0 = nbeg; n0 < nbeg + SEGLEN; n0 += 64) {
        // ---- K/V fragment loads (shared by all 4 m-subtiles) ----
        const __hip_bfloat16* kt =
            kS + (((size_t)b * KTILES + (n0 >> 4)) << 10) + lane * 8;
        bf16x8 ka[8];
        #pragma unroll
        for (int j = 0; j < 4; j++) {
            ka[2 * j]     = *(const bf16x8*)(kt + (j << 10));
            ka[2 * j + 1] = *(const bf16x8*)(kt + (j << 10) + 512);
        }
        const __hip_bfloat16* vt =
            vS + ((((size_t)b * VTILES) + (n0 >> 6)) << 12) + lane * 8;
        bf16x8 va[8];
        #pragma unroll
        for (int cc = 0; cc < 4; cc++) {
            va[2 * cc]     = *(const bf16x8*)(vt + cc * 1024);
            va[2 * cc + 1] = *(const bf16x8*)(vt + cc * 1024 + 512);
        }

        // ---- per m-subtile: S^T -> exp2 -> PV (s regs transient) ----
        #pragma unroll
        for (int ms = 0; ms < 4; ms++) {
            f32x4 s[4];
            #pragma unroll
            for (int j = 0; j < 4; j++) {
                s[j] = __builtin_amdgcn_mfma_f32_16x16x32_bf16(
                           ka[2 * j], qa[ms][0], (f32x4){0.f, 0.f, 0.f, 0.f}, 0, 0, 0);
                s[j] = __builtin_amdgcn_mfma_f32_16x16x32_bf16(
                           ka[2 * j + 1], qa[ms][1], s[j], 0, 0, 0);
            }
            union { __hip_bfloat16 e[8]; bf16x8 v; } p0, p1;
            float ps = 0.f;
            #pragma unroll
            for (int j = 0; j < 2; j++)
                #pragma unroll
                for (int r = 0; r < 4; r++) {
                    float e0 = __builtin_amdgcn_exp2f(s[j][r]);
                    float e1 = __builtin_amdgcn_exp2f(s[2 + j][r]);
                    ps += e0 + e1;
                    p0.e[j * 4 + r] = __float2bfloat16(e0);
                    p1.e[j * 4 + r] = __float2bfloat16(e1);
                }
            rsum[ms] += ps;
            #pragma unroll
            for (int cc = 0; cc < 4; cc++) {
                accO[ms][cc] = __builtin_amdgcn_mfma_f32_16x16x32_bf16(
                                   va[2 * cc], p0.v, accO[ms][cc], 0, 0, 0);
                accO[ms][cc] = __builtin_amdgcn_mfma_f32_16x16x32_bf16(
                                   va[2 * cc + 1], p1.v, accO[ms][cc], 0, 0, 0);
            }
        }
    }

    // ---- finalize per-wave stats ----
    #pragma unroll
    for (int ms = 0; ms < 4; ms++) {
        rsum[ms] += __shfl_xor(rsum[ms], 16);
        rsum[ms] += __shfl_xor(rsum[ms], 32);
    }
    if (quad == 0) {
        #pragma unroll
        for (int ms = 0; ms < 4; ms++) lstat[wave][ms * 16 + col] = rsum[ms];
    }

    // ---- four-phase combine over 8 segments (o_lds reused per phase) ----
    #pragma unroll
    for (int phase = 0; phase < 4; phase++) {
        #pragma unroll
        for (int cc = 0; cc < 4; cc++)
            *(f32x4*)(o_lds + (wave * 16 + col) * OSTR + cc * 16 + quad * 4) =
                accO[phase][cc];
        __syncthreads();
        if (threadIdx.x < 256) {
            const int m  = threadIdx.x & 15;
            const int cq = threadIdx.x >> 4;
            const int mi = phase * 16 + m;
            float lsum = 0.f;
            f32x4 oacc = (f32x4){0.f, 0.f, 0.f, 0.f};
            #pragma unroll
            for (int sgm = 0; sgm < NSEG; sgm++) {
                lsum += lstat[sgm][mi];
                oacc += *(const f32x4*)(o_lds + (sgm * 16 + m) * OSTR + cq * 4);
            }
            const float inv = 1.0f / lsum;
            #pragma unroll
            for (int r = 0; r < 4; r++) {
                const int c = cq * 4 + r;
                out[(size_t)(b * C_DIM + c) * N_TOK + m0 + phase * 16 + m] =
                    oacc[r] * inv;
            }
        }
        __syncthreads();
    }
}

extern "C" void kernel_launch(void* const* d_in, const int* in_sizes, int n_in,
                              void* d_out, int out_size, void* d_ws, size_t ws_size,
                              hipStream_t stream) {
    const float* x  = (const float*)d_in[0];
    const float* h  = (const float*)d_in[1];
    const float* Wq = (const float*)d_in[2];
    const float* bq = (const float*)d_in[3];
    const float* Wk = (const float*)d_in[4];
    const float* bk = (const float*)d_in[5];
    const float* Wv = (const float*)d_in[6];
    const float* bv = (const float*)d_in[7];
    float* out = (float*)d_out;

    const size_t elems = (size_t)B_SZ * N_TOK * C_DIM;   // 589824
    __hip_bfloat16* qS = (__hip_bfloat16*)d_ws;
    __hip_bfloat16* kS = qS + elems;
    __hip_bfloat16* vS = kS + elems;

    proj_kernel<<<B_SZ * NBLK, 256, 0, stream>>>(x, h, Wq, bq, Wk, bk, Wv, bv,
                                                 qS, kS, vS);
    attn_kernel<<<B_SZ * M64BLKS, 512, 0, stream>>>(qS, kS, vS, out);
}